// Round 2
// baseline (8063.311 us; speedup 1.0000x reference)
//
#include <hip/hip_runtime.h>

typedef __attribute__((ext_vector_type(8))) _Float16 f16x8;
typedef __attribute__((ext_vector_type(4))) float f32x4;

#define B_SZ 64
#define T_SZ 512
#define I_SZ 512
#define H_SZ 1024
#define G4   4096

// ---------- prep: transpose + gate-interleave weights ----------
// src: [R][1024] fp32 (gate q's U or V). dst: [4096][R] f16, dst[4*n+q][r] = src[r][n]
__global__ void trans_kernel(const float* __restrict__ src, _Float16* __restrict__ dst,
                             int R, int q) {
  __shared__ float tile[64][65];
  const int n0 = blockIdx.x * 64;
  const int r0 = blockIdx.y * 64;
  const int x = threadIdx.x & 63, y = threadIdx.x >> 6;
  #pragma unroll
  for (int it = 0; it < 16; ++it) {
    int r = y * 16 + it;
    tile[r][x] = src[(size_t)(r0 + r) * H_SZ + n0 + x];
  }
  __syncthreads();
  #pragma unroll
  for (int it = 0; it < 16; ++it) {
    int rn = y * 16 + it;
    dst[(size_t)(4 * (n0 + rn) + q) * R + r0 + x] = (_Float16)tile[x][rn];
  }
}

// ---------- prep: interleave bias ----------
__global__ void bias_kernel(const float* __restrict__ b0, const float* __restrict__ b1,
                            const float* __restrict__ b2, const float* __restrict__ b3,
                            float* __restrict__ dst) {
  int g = blockIdx.x * blockDim.x + threadIdx.x;
  if (g >= G4) return;
  int q = g & 3, n = g >> 2;
  const float* s = (q == 0) ? b0 : (q == 1) ? b1 : (q == 2) ? b2 : b3;
  dst[g] = s[n];
}

// ---------- one timestep ----------
// 256 blocks x 256 thr. blk = bgrp*64 + hgrp (hgrp-major => weight slice for hgrp
// lives on XCD hgrp%8 for all 4 batch groups -> stays L2-resident).
// Wave: 16 interleaved gate cols (4 hidden x {i,f,c,o}) x 16 batches.
// Kernel boundary = the grid-wide sync (no cooperative launch, no coherence risk).
__global__ __launch_bounds__(256) void lstm_step(
    const float* __restrict__ x,        // [B][T][I] fp32
    const _Float16* __restrict__ Ubt,   // [4096][512]  row 4n+q = U_q[:,n]
    const _Float16* __restrict__ Vt,    // [4096][1024] row 4n+q = V_q[:,n]
    const float* __restrict__ biasw,    // [4096] interleaved
    float* __restrict__ out,            // hidden_seq | h_T | c_T
    _Float16* __restrict__ hbuf,        // [2][64][1024] f16 double buffer
    float* __restrict__ cbuf,           // [64][1024] fp32 c-state
    int t)
{
  const int tid  = threadIdx.x;
  const int wv   = tid >> 6;
  const int lane = tid & 63;
  const int lc   = lane & 15;     // col-in-wave / A-row sel
  const int lk   = lane >> 4;     // k-group
  const int q    = lc & 3;        // gate id (0=i,1=f,2=g,3=o)
  const int bgrp = blockIdx.x >> 6;       // 0..3
  const int hgrp = blockIdx.x & 63;       // 0..63
  const int col0 = hgrp * 64 + wv * 16;   // interleaved gate-col base
  const int b0   = bgrp * 16;             // batch base

  const _Float16* hcur  = hbuf + (size_t)(t & 1) * (B_SZ * H_SZ);
  _Float16*       hnext = hbuf + (size_t)((t + 1) & 1) * (B_SZ * H_SZ);

  const float bias_v = biasw[col0 + lc];
  f32x4 acc0 = {bias_v, bias_v, bias_v, bias_v};
  f32x4 acc1 = {0.f, 0.f, 0.f, 0.f};

  // x projection (fused): A rows = batch, K = I, fp32 -> f16 on the fly
  const float* xp = x + ((size_t)(b0 + lc) * T_SZ + t) * I_SZ + lk * 8;
  const _Float16* up = Ubt + (size_t)(col0 + lc) * I_SZ + lk * 8;
  #pragma unroll
  for (int ks = 0; ks < 16; ++ks) {
    const float4 xa = *(const float4*)(xp + ks * 32);
    const float4 xb = *(const float4*)(xp + ks * 32 + 4);
    f16x8 a = { (_Float16)xa.x, (_Float16)xa.y, (_Float16)xa.z, (_Float16)xa.w,
                (_Float16)xb.x, (_Float16)xb.y, (_Float16)xb.z, (_Float16)xb.w };
    const f16x8 b = *(const f16x8*)(up + ks * 32);
    if (ks & 1) acc1 = __builtin_amdgcn_mfma_f32_16x16x32_f16(a, b, acc1, 0, 0, 0);
    else        acc0 = __builtin_amdgcn_mfma_f32_16x16x32_f16(a, b, acc0, 0, 0, 0);
  }
  // h projection: K = H
  const _Float16* hp = hcur + (size_t)(b0 + lc) * H_SZ + lk * 8;
  const _Float16* vp = Vt + (size_t)(col0 + lc) * H_SZ + lk * 8;
  #pragma unroll
  for (int ks = 0; ks < 32; ++ks) {
    const f16x8 a = *(const f16x8*)(hp + ks * 32);
    const f16x8 b = *(const f16x8*)(vp + ks * 32);
    if (ks & 1) acc1 = __builtin_amdgcn_mfma_f32_16x16x32_f16(a, b, acc1, 0, 0, 0);
    else        acc0 = __builtin_amdgcn_mfma_f32_16x16x32_f16(a, b, acc0, 0, 0, 0);
  }

  // elementwise: lane holds gate q of hidden n_glob for D rows b0+lk*4+r
  const int n_glob = hgrp * 16 + wv * 4 + (lc >> 2);
  const size_t HO = (size_t)B_SZ * T_SZ * H_SZ;
  const size_t CO = HO + (size_t)B_SZ * H_SZ;
  #pragma unroll
  for (int r = 0; r < 4; ++r) {
    const int b = b0 + lk * 4 + r;
    const float cold = cbuf[(size_t)b * H_SZ + n_glob];  // all 4 q-lanes load (lockstep, pre-store)
    const float v  = acc0[r] + acc1[r];
    const float sc = (q == 2) ? 2.f : 1.f;
    const float s  = 1.f / (1.f + __expf(-sc * v));
    const float av = (q == 2) ? (2.f * s - 1.f) : s;   // tanh via 2*sigm(2x)-1
    const float x1 = __shfl_xor(av, 1);
    const float x2 = __shfl_xor(av, 2);
    const float x3 = __shfl_xor(av, 3);
    const float gi = (q == 0) ? av : (q == 1) ? x1 : (q == 2) ? x2 : x3;
    const int m1 = q ^ 1;
    const float gf = (m1 == 0) ? av : (m1 == 1) ? x1 : (m1 == 2) ? x2 : x3;
    const int m2 = q ^ 2;
    const float gg = (m2 == 0) ? av : (m2 == 1) ? x1 : (m2 == 2) ? x2 : x3;
    const int m3 = q ^ 3;
    const float go = (m3 == 0) ? av : (m3 == 1) ? x1 : (m3 == 2) ? x2 : x3;
    const float cn = gf * cold + gi * gg;
    const float s2 = 1.f / (1.f + __expf(-2.f * cn));
    const float hn = go * (2.f * s2 - 1.f);
    if (q == 0) {
      out[(size_t)b * (T_SZ * H_SZ) + (size_t)t * H_SZ + n_glob] = hn;
      hnext[(size_t)b * H_SZ + n_glob] = (_Float16)hn;
      cbuf[(size_t)b * H_SZ + n_glob] = cn;
      if (t == T_SZ - 1) {
        out[HO + (size_t)b * H_SZ + n_glob] = hn;
        out[CO + (size_t)b * H_SZ + n_glob] = cn;
      }
    }
  }
}

extern "C" void kernel_launch(void* const* d_in, const int* in_sizes, int n_in,
                              void* d_out, int out_size, void* d_ws, size_t ws_size,
                              hipStream_t stream) {
  const float* x = (const float*)d_in[0];
  const float* U[4]  = {(const float*)d_in[1], (const float*)d_in[4],
                        (const float*)d_in[7], (const float*)d_in[10]};
  const float* V[4]  = {(const float*)d_in[2], (const float*)d_in[5],
                        (const float*)d_in[8], (const float*)d_in[11]};
  const float* bb[4] = {(const float*)d_in[3], (const float*)d_in[6],
                        (const float*)d_in[9], (const float*)d_in[12]};
  float* out = (float*)d_out;

  char* p = (char*)d_ws;
  _Float16* Ubt = (_Float16*)p; p += (size_t)G4 * I_SZ * 2;   // 4 MB
  _Float16* Vt  = (_Float16*)p; p += (size_t)G4 * H_SZ * 2;   // 8 MB
  float*    biasw = (float*)p;  p += (size_t)G4 * 4;          // 16 KB
  _Float16* hbuf  = (_Float16*)p; p += (size_t)2 * B_SZ * H_SZ * 2; // 256 KB
  float*    cbuf  = (float*)p;                                 // 256 KB

  for (int qq = 0; qq < 4; ++qq)
    hipLaunchKernelGGL(trans_kernel, dim3(16, 8), dim3(256), 0, stream, U[qq], Ubt, I_SZ, qq);
  for (int qq = 0; qq < 4; ++qq)
    hipLaunchKernelGGL(trans_kernel, dim3(16, 16), dim3(256), 0, stream, V[qq], Vt, H_SZ, qq);
  hipLaunchKernelGGL(bias_kernel, dim3(16), dim3(256), 0, stream, bb[0], bb[1], bb[2], bb[3], biasw);

  // zero h(0) (both h buffers) and c(0)
  hipMemsetAsync(hbuf, 0, (size_t)2 * B_SZ * H_SZ * 2 + (size_t)B_SZ * H_SZ * 4, stream);

  for (int t = 0; t < T_SZ; ++t)
    hipLaunchKernelGGL(lstm_step, dim3(256), dim3(256), 0, stream,
                       x, Ubt, Vt, biasw, out, hbuf, cbuf, t);
}